// Round 1
// baseline (165.865 us; speedup 1.0000x reference)
//
#include <hip/hip_runtime.h>

#define NUM_NODES 100000
#define NUM_EDGES 400000
#define F_IN 16
#define F_EDGE 8
#define EMB 16
#define NUM_GRAPHS 256

#define EDGE_TILES 5                                   // 32-edge tiles per block
#define EDGE_BLOCKS (NUM_EDGES / (32 * EDGE_TILES))    // 2500

#define NPB 128                                        // nodes per node_kernel block
#define NODE_BLOCKS ((NUM_NODES + NPB - 1) / NPB)      // 782

// ---------------------------------------------------------------------------
// Workspace (zeroed each launch):
//   sums : NUM_NODES*EMB f32, cnt : NUM_NODES f32,
//   gmax : NUM_GRAPHS*EMB u32 (float bits, h>=0 so uint order == float order),
//   gsum : NUM_GRAPHS*EMB f32, gcnt : NUM_GRAPHS f32
// ---------------------------------------------------------------------------

// Block = 256 threads (eL 0..15, o 0..15); tile = 32 edges; thread handles
// edges (tile+eL) and (tile+16+eL) sharing one LDS weight read per i.
// NO barriers inside the tile loop.
//
// v2: software-pipelined. All 5 tiles' src indices are preloaded at kernel
// start (latency hides under weight staging + the single barrier); ea/x/dst
// for tile t+1 are issued into the alternate register buffer BEFORE tile t's
// FMA chain, so the two-deep dependent chain (ei -> x[src]) never stalls the
// VALU in steady state. launch_bounds(256,3) caps VGPR at 170 (3 waves/SIMD);
// liveness estimate ~150 so no spills expected.
__global__ __launch_bounds__(256, 3) void edge_kernel(
    const float* __restrict__ x, const int* __restrict__ ei,
    const float* __restrict__ ea, const float* __restrict__ nn1_w,
    const float* __restrict__ nn1_b, float* __restrict__ sums,
    float* __restrict__ cnt)
{
    __shared__ float wtp[256 * 12];   // row r=(i*16+o): 8 weights + 4 pad
    __shared__ float btp[16 * 20];    // btp[o*20+i]

    const int tid = threadIdx.x;
    const int eL  = tid >> 4;
    const int o   = tid & 15;
    const int eb0 = blockIdx.x * EDGE_TILES * 32;

    // ---- issue all src-index loads immediately (latency hides under staging)
    int srcA[EDGE_TILES], srcB[EDGE_TILES];
    #pragma unroll
    for (int t = 0; t < EDGE_TILES; t++) {
        srcA[t] = ei[eb0 + t * 32 + eL];
        srcB[t] = ei[eb0 + t * 32 + 16 + eL];
    }

    // ---- stage weights, vectorized: thread tid owns row tid (16B-aligned,
    //      row stride 12 floats = 48B; bank 12r mod 32 -> 2-way = free)
    {
        const float4 w0 = *(const float4*)&nn1_w[tid * 8];
        const float4 w1 = *(const float4*)&nn1_w[tid * 8 + 4];
        *(float4*)&wtp[tid * 12]     = w0;
        *(float4*)&wtp[tid * 12 + 4] = w1;
    }
    btp[(tid & 15) * 20 + (tid >> 4)] = nn1_b[tid];   // tid = i*16+o
    __syncthreads();                                   // the ONLY barrier

    float br[F_IN];
    #pragma unroll
    for (int r = 0; r < 4; r++) {
        const float4 b4 = *(const float4*)&btp[o * 20 + 4 * r];
        br[4 * r + 0] = b4.x; br[4 * r + 1] = b4.y;
        br[4 * r + 2] = b4.z; br[4 * r + 3] = b4.w;
    }

    // ---- double-buffered tile state (p = even tiles, q = odd tiles)
    float4 pA00, pA01, pA10, pA11; float pX0[16], pX1[16]; int pDA, pDB;
    float4 qA00, qA01, qA10, qA11; float qX0[16], qX1[16]; int qDA, qDB;

    // T must be a compile-time constant at every expansion (loop fully
    // unrolled) so srcA[T]/srcB[T] stay in registers, not scratch.
#define LOAD_TILE(T, A00, A01, A10, A11, X0, X1, DA, DB) do {               \
        const int eA_ = eb0 + (T) * 32 + eL;                                \
        const int eB_ = eA_ + 16;                                           \
        DA = ei[NUM_EDGES + eA_];                                           \
        DB = ei[NUM_EDGES + eB_];                                           \
        A00 = *(const float4*)&ea[eA_ * 8];                                 \
        A01 = *(const float4*)&ea[eA_ * 8 + 4];                             \
        A10 = *(const float4*)&ea[eB_ * 8];                                 \
        A11 = *(const float4*)&ea[eB_ * 8 + 4];                             \
        _Pragma("unroll")                                                   \
        for (int r = 0; r < 4; r++) {                                       \
            const float4 v0 = *(const float4*)&x[srcA[T] * 16 + 4 * r];     \
            const float4 v1 = *(const float4*)&x[srcB[T] * 16 + 4 * r];     \
            X0[4*r+0] = v0.x; X0[4*r+1] = v0.y;                             \
            X0[4*r+2] = v0.z; X0[4*r+3] = v0.w;                             \
            X1[4*r+0] = v1.x; X1[4*r+1] = v1.y;                             \
            X1[4*r+2] = v1.z; X1[4*r+3] = v1.w;                             \
        }                                                                   \
    } while (0)

    // FMA ordering identical to v1 (bit-exact output preserved).
#define COMPUTE_TILE(A00, A01, A10, A11, X0, X1, DA, DB) do {               \
        float acc0 = 0.f, acc1 = 0.f;                                       \
        _Pragma("unroll")                                                   \
        for (int i = 0; i < F_IN; i++) {                                    \
            const float* wr = &wtp[(i * 16 + o) * 12];                      \
            const float4 w0 = *(const float4*)wr;                           \
            const float4 w1 = *(const float4*)(wr + 4);                     \
            float u = br[i];                                                \
            u = fmaf(A00.x, w0.x, u); u = fmaf(A00.y, w0.y, u);             \
            u = fmaf(A00.z, w0.z, u); u = fmaf(A00.w, w0.w, u);             \
            u = fmaf(A01.x, w1.x, u); u = fmaf(A01.y, w1.y, u);             \
            u = fmaf(A01.z, w1.z, u); u = fmaf(A01.w, w1.w, u);             \
            acc0 = fmaf(X0[i], fmaxf(u, 0.f), acc0);                        \
            float v = br[i];                                                \
            v = fmaf(A10.x, w0.x, v); v = fmaf(A10.y, w0.y, v);             \
            v = fmaf(A10.z, w0.z, v); v = fmaf(A10.w, w0.w, v);             \
            v = fmaf(A11.x, w1.x, v); v = fmaf(A11.y, w1.y, v);             \
            v = fmaf(A11.z, w1.z, v); v = fmaf(A11.w, w1.w, v);             \
            acc1 = fmaf(X1[i], fmaxf(v, 0.f), acc1);                        \
        }                                                                   \
        atomicAdd(&sums[DA * 16 + o], acc0);                                \
        atomicAdd(&sums[DB * 16 + o], acc1);                                \
        if (o == 0) {                                                       \
            atomicAdd(&cnt[DA], 1.f);                                       \
            atomicAdd(&cnt[DB], 1.f);                                       \
        }                                                                   \
    } while (0)

    LOAD_TILE(0, pA00, pA01, pA10, pA11, pX0, pX1, pDA, pDB);
    #pragma unroll
    for (int t = 0; t < EDGE_TILES; t++) {
        if ((t & 1) == 0) {
            if (t + 1 < EDGE_TILES)
                LOAD_TILE(t + 1, qA00, qA01, qA10, qA11, qX0, qX1, qDA, qDB);
            COMPUTE_TILE(pA00, pA01, pA10, pA11, pX0, pX1, pDA, pDB);
        } else {
            if (t + 1 < EDGE_TILES)
                LOAD_TILE(t + 1, pA00, pA01, pA10, pA11, pX0, pX1, pDA, pDB);
            COMPUTE_TILE(qA00, qA01, qA10, qA11, qX0, qX1, qDA, qDB);
        }
    }
#undef LOAD_TILE
#undef COMPUTE_TILE
}

// One block per 128 nodes. Computes h = relu(agg + x@root_w^T + conv_b) in
// 16-node sub-tiles; 16 flusher threads carry per-channel (max,sum,count)
// accumulators in REGISTERS across sub-tiles, hitting global atomics only on
// graph-boundary or block-end (~1-2 flushes/block -> ~64 same-line ops/graph).
__global__ __launch_bounds__(256) void node_kernel(
    const float* __restrict__ x, const int* __restrict__ batch,
    const float* __restrict__ root_w, const float* __restrict__ conv_b,
    const float* __restrict__ sums, const float* __restrict__ cnt,
    unsigned int* __restrict__ gmax, float* __restrict__ gsum,
    float* __restrict__ gcnt)
{
    __shared__ float rwT[256];   // rwT[i*16+o] = root_w[o*16+i]
    __shared__ float xsh[256];
    __shared__ float ssh[256];
    __shared__ float csh[16];
    __shared__ int   bsh[16];
    __shared__ float hsh[256];

    const int tid = threadIdx.x;
    const int j   = tid >> 4;
    const int o   = tid & 15;
    const int n0  = blockIdx.x * NPB;

    rwT[(tid & 15) * 16 + (tid >> 4)] = root_w[tid];
    const float cb = conv_b[o];

    // flusher state (threads 0..15; lockstep, same wave)
    int   curg = batch[n0];      // n0 < NUM_NODES for all 782 blocks
    float am = 0.f, asum = 0.f, ac = 0.f;

    for (int s0 = 0; s0 < NPB; s0 += 16) {
        const int base = n0 + s0;
        const int idx  = base * 16 + tid;
        const bool v   = (idx < NUM_NODES * 16);
        const float xv = v ? x[idx]    : 0.f;
        const float sv = v ? sums[idx] : 0.f;
        float cv = 1.f; int bv = -1;
        if (tid < 16) {
            const int n = base + tid;
            if (n < NUM_NODES) { cv = cnt[n]; bv = batch[n]; }
        }
        __syncthreads();   // prev sub-tile's hsh/bsh fully consumed
        xsh[tid] = xv; ssh[tid] = sv;
        if (tid < 16) { csh[tid] = cv; bsh[tid] = bv; }
        __syncthreads();

        float a = cb + ssh[j * 16 + o] / fmaxf(csh[j], 1.f);
        #pragma unroll
        for (int i = 0; i < F_IN; i++)
            a = fmaf(xsh[j * 16 + i], rwT[i * 16 + o], a);
        hsh[tid] = fmaxf(a, 0.f);
        __syncthreads();   // hsh ready

        if (tid < 16) {
            #pragma unroll 1
            for (int jj = 0; jj < 16; jj++) {
                const int g = bsh[jj];
                if (g < 0) break;              // past last node
                if (g != curg) {
                    atomicMax(&gmax[curg * 16 + o], __float_as_uint(am));
                    atomicAdd(&gsum[curg * 16 + o], asum);
                    if (o == 0) atomicAdd(&gcnt[curg], ac);
                    am = 0.f; asum = 0.f; ac = 0.f; curg = g;
                }
                const float h = hsh[jj * 16 + o];
                am = fmaxf(am, h); asum += h; ac += 1.f;
            }
        }
    }

    if (tid < 16) {   // final flush
        atomicMax(&gmax[curg * 16 + o], __float_as_uint(am));
        atomicAdd(&gsum[curg * 16 + o], asum);
        if (o == 0) atomicAdd(&gcnt[curg], ac);
    }
}

// Head MLP: one thread per graph, single block.
__global__ __launch_bounds__(256) void head_kernel(
    const unsigned int* __restrict__ gmax, const float* __restrict__ gsum,
    const float* __restrict__ gcnt,
    const float* __restrict__ lin1_w, const float* __restrict__ lin1_b,
    const float* __restrict__ lin2_w, const float* __restrict__ lin2_b,
    float* __restrict__ out)
{
    const int g = threadIdx.x;

    float pooled[2 * EMB];
    #pragma unroll
    for (int o = 0; o < EMB; o++) pooled[o] = __uint_as_float(gmax[g * 16 + o]);
    const float c = fmaxf(gcnt[g], 1.f);
    #pragma unroll
    for (int o = 0; o < EMB; o++) pooled[EMB + o] = gsum[g * 16 + o] / c;

    float acc = lin2_b[0];
    #pragma unroll
    for (int k = 0; k < EMB; k++) {
        float a = lin1_b[k];
        #pragma unroll
        for (int cc = 0; cc < 2 * EMB; cc++)
            a = fmaf(pooled[cc], lin1_w[k * 32 + cc], a);
        acc = fmaf(fmaxf(a, 0.f), lin2_w[k], acc);
    }
    out[g] = acc;
}

extern "C" void kernel_launch(void* const* d_in, const int* in_sizes, int n_in,
                              void* d_out, int out_size, void* d_ws, size_t ws_size,
                              hipStream_t stream) {
    const float* x      = (const float*)d_in[0];
    const int*   ei     = (const int*)d_in[1];
    const float* ea     = (const float*)d_in[2];
    const int*   batch  = (const int*)d_in[3];
    const float* nn1_w  = (const float*)d_in[4];
    const float* nn1_b  = (const float*)d_in[5];
    const float* root_w = (const float*)d_in[6];
    const float* conv_b = (const float*)d_in[7];
    const float* lin1_w = (const float*)d_in[8];
    const float* lin1_b = (const float*)d_in[9];
    const float* lin2_w = (const float*)d_in[10];
    const float* lin2_b = (const float*)d_in[11];
    float* out = (float*)d_out;

    float*        sums = (float*)d_ws;
    float*        cnt  = sums + (size_t)NUM_NODES * EMB;
    unsigned int* gmax = (unsigned int*)(cnt + NUM_NODES);
    float*        gsum = (float*)(gmax + NUM_GRAPHS * EMB);
    float*        gcnt = gsum + NUM_GRAPHS * EMB;

    const size_t zero_bytes = sizeof(float) *
        ((size_t)NUM_NODES * EMB + NUM_NODES + 2 * NUM_GRAPHS * EMB + NUM_GRAPHS);
    hipMemsetAsync(d_ws, 0, zero_bytes, stream);

    edge_kernel<<<EDGE_BLOCKS, 256, 0, stream>>>(x, ei, ea, nn1_w, nn1_b, sums, cnt);
    node_kernel<<<NODE_BLOCKS, 256, 0, stream>>>(
        x, batch, root_w, conv_b, sums, cnt, gmax, gsum, gcnt);
    head_kernel<<<1, 256, 0, stream>>>(gmax, gsum, gcnt,
                                       lin1_w, lin1_b, lin2_w, lin2_b, out);
}

// Round 2
// 163.532 us; speedup vs baseline: 1.0143x; 1.0143x over previous
//
#include <hip/hip_runtime.h>

#define NUM_NODES 100000
#define NUM_EDGES 400000
#define F_IN 16
#define F_EDGE 8
#define EMB 16
#define NUM_GRAPHS 256

#define EDGE_TILES 5                                   // 32-edge tiles per block
#define EDGE_BLOCKS (NUM_EDGES / (32 * EDGE_TILES))    // 2500

#define NPB 128                                        // nodes per node_kernel block
#define NODE_BLOCKS ((NUM_NODES + NPB - 1) / NPB)      // 782

// ---------------------------------------------------------------------------
// Workspace (zeroed each launch):
//   sums : NUM_NODES*EMB f32, cnt : NUM_NODES f32,
//   gmax : NUM_GRAPHS*EMB u32 (float bits, h>=0 so uint order == float order),
//   gsum : NUM_GRAPHS*EMB f32, gcnt : NUM_GRAPHS f32
// ---------------------------------------------------------------------------

// Block = 256 threads (eL 0..15, o 0..15); tile = 32 edges; thread handles
// edges (tile+eL) and (tile+16+eL) sharing one LDS weight read per i.
// NO barriers inside the tile loop.
//
// v3: v2's software pipeline, but FORCED with sched_barrier(0) fences.
// v2's lesson: without fences the compiler re-sinks the prefetch loads to
// their uses (VGPR fell to 68, VALUBusy stayed 45%). Fences:
//   (a) after the src-index preload -> ei loads issue before weight staging;
//   (b) between LOAD_TILE(t+1) and COMPUTE_TILE(t) -> next tile's ea/x/dst
//       loads are in flight across the whole FMA chain of tile t. Their
//       waitcnt lands at first use (compute t+1) at vmcnt(~4) — tile t's
//       fire-and-forget atomics stay in flight, never drained.
// Nothing inside COMPUTE_TILE is pinned (coarse fences only, m141 lesson).
__global__ __launch_bounds__(256, 3) void edge_kernel(
    const float* __restrict__ x, const int* __restrict__ ei,
    const float* __restrict__ ea, const float* __restrict__ nn1_w,
    const float* __restrict__ nn1_b, float* __restrict__ sums,
    float* __restrict__ cnt)
{
    __shared__ float wtp[256 * 12];   // row r=(i*16+o): 8 weights + 4 pad
    __shared__ float btp[16 * 20];    // btp[o*20+i]

    const int tid = threadIdx.x;
    const int eL  = tid >> 4;
    const int o   = tid & 15;
    const int eb0 = blockIdx.x * EDGE_TILES * 32;

    // ---- issue all src-index loads immediately (latency hides under staging)
    int srcA[EDGE_TILES], srcB[EDGE_TILES];
    #pragma unroll
    for (int t = 0; t < EDGE_TILES; t++) {
        srcA[t] = ei[eb0 + t * 32 + eL];
        srcB[t] = ei[eb0 + t * 32 + 16 + eL];
    }
    __builtin_amdgcn_sched_barrier(0);   // pin: src loads issue FIRST

    // ---- stage weights, vectorized: thread tid owns row tid (16B-aligned,
    //      row stride 12 floats = 48B; bank 12r mod 32 -> 2-way = free)
    {
        const float4 w0 = *(const float4*)&nn1_w[tid * 8];
        const float4 w1 = *(const float4*)&nn1_w[tid * 8 + 4];
        *(float4*)&wtp[tid * 12]     = w0;
        *(float4*)&wtp[tid * 12 + 4] = w1;
    }
    btp[(tid & 15) * 20 + (tid >> 4)] = nn1_b[tid];   // tid = i*16+o
    __syncthreads();                                   // the ONLY barrier

    float br[F_IN];
    #pragma unroll
    for (int r = 0; r < 4; r++) {
        const float4 b4 = *(const float4*)&btp[o * 20 + 4 * r];
        br[4 * r + 0] = b4.x; br[4 * r + 1] = b4.y;
        br[4 * r + 2] = b4.z; br[4 * r + 3] = b4.w;
    }

    // ---- double-buffered tile state (p = even tiles, q = odd tiles)
    float4 pA00, pA01, pA10, pA11; float pX0[16], pX1[16]; int pDA, pDB;
    float4 qA00, qA01, qA10, qA11; float qX0[16], qX1[16]; int qDA, qDB;

    // T must be a compile-time constant at every expansion (loop fully
    // unrolled) so srcA[T]/srcB[T] stay in registers, not scratch.
#define LOAD_TILE(T, A00, A01, A10, A11, X0, X1, DA, DB) do {               \
        const int eA_ = eb0 + (T) * 32 + eL;                                \
        const int eB_ = eA_ + 16;                                           \
        DA = ei[NUM_EDGES + eA_];                                           \
        DB = ei[NUM_EDGES + eB_];                                           \
        A00 = *(const float4*)&ea[eA_ * 8];                                 \
        A01 = *(const float4*)&ea[eA_ * 8 + 4];                             \
        A10 = *(const float4*)&ea[eB_ * 8];                                 \
        A11 = *(const float4*)&ea[eB_ * 8 + 4];                             \
        _Pragma("unroll")                                                   \
        for (int r = 0; r < 4; r++) {                                       \
            const float4 v0 = *(const float4*)&x[srcA[T] * 16 + 4 * r];     \
            const float4 v1 = *(const float4*)&x[srcB[T] * 16 + 4 * r];     \
            X0[4*r+0] = v0.x; X0[4*r+1] = v0.y;                             \
            X0[4*r+2] = v0.z; X0[4*r+3] = v0.w;                             \
            X1[4*r+0] = v1.x; X1[4*r+1] = v1.y;                             \
            X1[4*r+2] = v1.z; X1[4*r+3] = v1.w;                             \
        }                                                                   \
    } while (0)

    // FMA ordering identical to v1 (bit-exact output preserved).
#define COMPUTE_TILE(A00, A01, A10, A11, X0, X1, DA, DB) do {               \
        float acc0 = 0.f, acc1 = 0.f;                                       \
        _Pragma("unroll")                                                   \
        for (int i = 0; i < F_IN; i++) {                                    \
            const float* wr = &wtp[(i * 16 + o) * 12];                      \
            const float4 w0 = *(const float4*)wr;                           \
            const float4 w1 = *(const float4*)(wr + 4);                     \
            float u = br[i];                                                \
            u = fmaf(A00.x, w0.x, u); u = fmaf(A00.y, w0.y, u);             \
            u = fmaf(A00.z, w0.z, u); u = fmaf(A00.w, w0.w, u);             \
            u = fmaf(A01.x, w1.x, u); u = fmaf(A01.y, w1.y, u);             \
            u = fmaf(A01.z, w1.z, u); u = fmaf(A01.w, w1.w, u);             \
            acc0 = fmaf(X0[i], fmaxf(u, 0.f), acc0);                        \
            float v = br[i];                                                \
            v = fmaf(A10.x, w0.x, v); v = fmaf(A10.y, w0.y, v);             \
            v = fmaf(A10.z, w0.z, v); v = fmaf(A10.w, w0.w, v);             \
            v = fmaf(A11.x, w1.x, v); v = fmaf(A11.y, w1.y, v);             \
            v = fmaf(A11.w, w1.w, v); v = fmaf(A11.z, w1.z, v);             \
            acc1 = fmaf(X1[i], fmaxf(v, 0.f), acc1);                        \
        }                                                                   \
        atomicAdd(&sums[DA * 16 + o], acc0);                                \
        atomicAdd(&sums[DB * 16 + o], acc1);                                \
        if (o == 0) {                                                       \
            atomicAdd(&cnt[DA], 1.f);                                       \
            atomicAdd(&cnt[DB], 1.f);                                       \
        }                                                                   \
    } while (0)

    LOAD_TILE(0, pA00, pA01, pA10, pA11, pX0, pX1, pDA, pDB);
    #pragma unroll
    for (int t = 0; t < EDGE_TILES; t++) {
        if ((t & 1) == 0) {
            if (t + 1 < EDGE_TILES)
                LOAD_TILE(t + 1, qA00, qA01, qA10, qA11, qX0, qX1, qDA, qDB);
            __builtin_amdgcn_sched_barrier(0);   // loads(t+1) stay above compute(t)
            COMPUTE_TILE(pA00, pA01, pA10, pA11, pX0, pX1, pDA, pDB);
        } else {
            if (t + 1 < EDGE_TILES)
                LOAD_TILE(t + 1, pA00, pA01, pA10, pA11, pX0, pX1, pDA, pDB);
            __builtin_amdgcn_sched_barrier(0);
            COMPUTE_TILE(qA00, qA01, qA10, qA11, qX0, qX1, qDA, qDB);
        }
    }
#undef LOAD_TILE
#undef COMPUTE_TILE
}

// One block per 128 nodes. Computes h = relu(agg + x@root_w^T + conv_b) in
// 16-node sub-tiles; 16 flusher threads carry per-channel (max,sum,count)
// accumulators in REGISTERS across sub-tiles, hitting global atomics only on
// graph-boundary or block-end (~1-2 flushes/block -> ~64 same-line ops/graph).
__global__ __launch_bounds__(256) void node_kernel(
    const float* __restrict__ x, const int* __restrict__ batch,
    const float* __restrict__ root_w, const float* __restrict__ conv_b,
    const float* __restrict__ sums, const float* __restrict__ cnt,
    unsigned int* __restrict__ gmax, float* __restrict__ gsum,
    float* __restrict__ gcnt)
{
    __shared__ float rwT[256];   // rwT[i*16+o] = root_w[o*16+i]
    __shared__ float xsh[256];
    __shared__ float ssh[256];
    __shared__ float csh[16];
    __shared__ int   bsh[16];
    __shared__ float hsh[256];

    const int tid = threadIdx.x;
    const int j   = tid >> 4;
    const int o   = tid & 15;
    const int n0  = blockIdx.x * NPB;

    rwT[(tid & 15) * 16 + (tid >> 4)] = root_w[tid];
    const float cb = conv_b[o];

    // flusher state (threads 0..15; lockstep, same wave)
    int   curg = batch[n0];      // n0 < NUM_NODES for all 782 blocks
    float am = 0.f, asum = 0.f, ac = 0.f;

    for (int s0 = 0; s0 < NPB; s0 += 16) {
        const int base = n0 + s0;
        const int idx  = base * 16 + tid;
        const bool v   = (idx < NUM_NODES * 16);
        const float xv = v ? x[idx]    : 0.f;
        const float sv = v ? sums[idx] : 0.f;
        float cv = 1.f; int bv = -1;
        if (tid < 16) {
            const int n = base + tid;
            if (n < NUM_NODES) { cv = cnt[n]; bv = batch[n]; }
        }
        __syncthreads();   // prev sub-tile's hsh/bsh fully consumed
        xsh[tid] = xv; ssh[tid] = sv;
        if (tid < 16) { csh[tid] = cv; bsh[tid] = bv; }
        __syncthreads();

        float a = cb + ssh[j * 16 + o] / fmaxf(csh[j], 1.f);
        #pragma unroll
        for (int i = 0; i < F_IN; i++)
            a = fmaf(xsh[j * 16 + i], rwT[i * 16 + o], a);
        hsh[tid] = fmaxf(a, 0.f);
        __syncthreads();   // hsh ready

        if (tid < 16) {
            #pragma unroll 1
            for (int jj = 0; jj < 16; jj++) {
                const int g = bsh[jj];
                if (g < 0) break;              // past last node
                if (g != curg) {
                    atomicMax(&gmax[curg * 16 + o], __float_as_uint(am));
                    atomicAdd(&gsum[curg * 16 + o], asum);
                    if (o == 0) atomicAdd(&gcnt[curg], ac);
                    am = 0.f; asum = 0.f; ac = 0.f; curg = g;
                }
                const float h = hsh[jj * 16 + o];
                am = fmaxf(am, h); asum += h; ac += 1.f;
            }
        }
    }

    if (tid < 16) {   // final flush
        atomicMax(&gmax[curg * 16 + o], __float_as_uint(am));
        atomicAdd(&gsum[curg * 16 + o], asum);
        if (o == 0) atomicAdd(&gcnt[curg], ac);
    }
}

// Head MLP: one thread per graph, single block.
__global__ __launch_bounds__(256) void head_kernel(
    const unsigned int* __restrict__ gmax, const float* __restrict__ gsum,
    const float* __restrict__ gcnt,
    const float* __restrict__ lin1_w, const float* __restrict__ lin1_b,
    const float* __restrict__ lin2_w, const float* __restrict__ lin2_b,
    float* __restrict__ out)
{
    const int g = threadIdx.x;

    float pooled[2 * EMB];
    #pragma unroll
    for (int o = 0; o < EMB; o++) pooled[o] = __uint_as_float(gmax[g * 16 + o]);
    const float c = fmaxf(gcnt[g], 1.f);
    #pragma unroll
    for (int o = 0; o < EMB; o++) pooled[EMB + o] = gsum[g * 16 + o] / c;

    float acc = lin2_b[0];
    #pragma unroll
    for (int k = 0; k < EMB; k++) {
        float a = lin1_b[k];
        #pragma unroll
        for (int cc = 0; cc < 2 * EMB; cc++)
            a = fmaf(pooled[cc], lin1_w[k * 32 + cc], a);
        acc = fmaf(fmaxf(a, 0.f), lin2_w[k], acc);
    }
    out[g] = acc;
}

extern "C" void kernel_launch(void* const* d_in, const int* in_sizes, int n_in,
                              void* d_out, int out_size, void* d_ws, size_t ws_size,
                              hipStream_t stream) {
    const float* x      = (const float*)d_in[0];
    const int*   ei     = (const int*)d_in[1];
    const float* ea     = (const float*)d_in[2];
    const int*   batch  = (const int*)d_in[3];
    const float* nn1_w  = (const float*)d_in[4];
    const float* nn1_b  = (const float*)d_in[5];
    const float* root_w = (const float*)d_in[6];
    const float* conv_b = (const float*)d_in[7];
    const float* lin1_w = (const float*)d_in[8];
    const float* lin1_b = (const float*)d_in[9];
    const float* lin2_w = (const float*)d_in[10];
    const float* lin2_b = (const float*)d_in[11];
    float* out = (float*)d_out;

    float*        sums = (float*)d_ws;
    float*        cnt  = sums + (size_t)NUM_NODES * EMB;
    unsigned int* gmax = (unsigned int*)(cnt + NUM_NODES);
    float*        gsum = (float*)(gmax + NUM_GRAPHS * EMB);
    float*        gcnt = gsum + NUM_GRAPHS * EMB;

    const size_t zero_bytes = sizeof(float) *
        ((size_t)NUM_NODES * EMB + NUM_NODES + 2 * NUM_GRAPHS * EMB + NUM_GRAPHS);
    hipMemsetAsync(d_ws, 0, zero_bytes, stream);

    edge_kernel<<<EDGE_BLOCKS, 256, 0, stream>>>(x, ei, ea, nn1_w, nn1_b, sums, cnt);
    node_kernel<<<NODE_BLOCKS, 256, 0, stream>>>(
        x, batch, root_w, conv_b, sums, cnt, gmax, gsum, gcnt);
    head_kernel<<<1, 256, 0, stream>>>(gmax, gsum, gcnt,
                                       lin1_w, lin1_b, lin2_w, lin2_b, out);
}